// Round 13
// baseline (449.022 us; speedup 1.0000x reference)
//
#include <hip/hip_runtime.h>
#include <hip/hip_bf16.h>

#define N_NODES 25000
#define N_EDGES 400000
#define NB_SCAN ((N_NODES + 255) / 256)   // 98
#define EDGE_TILES (N_EDGES / 16)          // 25000
#define TPW 2                              // tiles per wave (edge kernel)
#define EDGE_WAVES (EDGE_TILES / TPW)      // 12500
#define EDGE_BLOCKS512 ((EDGE_WAVES + 7) / 8)   // 1563 blocks of 8 waves
#define NODE_TILES ((N_NODES + 15) / 16)   // 1563
#define NODE_BLOCKS2 ((NODE_TILES + 1) / 2) // 782 (2 tiles/block)

typedef __attribute__((ext_vector_type(8))) short short8;
typedef __attribute__((ext_vector_type(4))) float f32x4;

// fast silu: v_rcp_f32 (<=1 ulp) instead of full-precision divide sequence
__device__ __forceinline__ float silu_f(float x) {
  return x * __builtin_amdgcn_rcpf(1.0f + __expf(-x));
}

__device__ __forceinline__ short f2bf_s(float x) {
  __hip_bfloat16 h = __float2bfloat16(x);
  return *reinterpret_cast<short*>(&h);
}
__device__ __forceinline__ float bf_s2f(short s) {
  __hip_bfloat16 h = *reinterpret_cast<__hip_bfloat16*>(&s);
  return __bfloat162float(h);
}

// --- shared MFMA helpers (layout identical to the verified k_edge path) ----
// A-frag from LDS tile T[k][m] (stride 17): A[m=n16][k=s*32+quad*8+j]
__device__ __forceinline__ void load_afrag(const float* T, int s, int quad, int n16,
                                           short8& ahi, short8& alo) {
#pragma unroll
  for (int j = 0; j < 8; ++j) {
    float tv = T[(s * 32 + quad * 8 + j) * 17 + n16];
    short hi = f2bf_s(tv);
    ahi[j] = hi;
    alo[j] = f2bf_s(tv - bf_s2f(hi));
  }
}
// B-frag from global W[k][n] (row-major, 64 cols): B[k=k0+j][n=col]
__device__ __forceinline__ void load_bfrag(const float* __restrict__ W, int k0, int col,
                                           short8& bhi, short8& blo) {
#pragma unroll
  for (int j = 0; j < 8; ++j) {
    float w = W[(k0 + j) * 64 + col];
    short hi = f2bf_s(w);
    bhi[j] = hi;
    blo[j] = f2bf_s(w - bf_s2f(hi));
  }
}
// split-bf16 3-product ~fp32 MFMA
__device__ __forceinline__ f32x4 mfma3(short8 ahi, short8 alo, short8 bhi, short8 blo,
                                       f32x4 acc) {
  acc = __builtin_amdgcn_mfma_f32_16x16x32_bf16(ahi, bhi, acc, 0, 0, 0);
  acc = __builtin_amdgcn_mfma_f32_16x16x32_bf16(ahi, blo, acc, 0, 0, 0);
  acc = __builtin_amdgcn_mfma_f32_16x16x32_bf16(alo, bhi, acc, 0, 0, 0);
  return acc;
}

// ---------------------------------------------------------------------------
// Merged one-time prep:
//   blocks 0..5    : eW2/deW2 fragment split
//   blocks 6..405  : node-weight fragment split
//   blocks 406..805: edge histogram
// ---------------------------------------------------------------------------
__global__ __launch_bounds__(256) void k_prep(
    const float* __restrict__ eW2, const float* __restrict__ deW2,
    short* __restrict__ w2p,
    const float* __restrict__ nW1, const float* __restrict__ nW2,
    const float* __restrict__ eW1, const float* __restrict__ deW1,
    short* __restrict__ w1p, short* __restrict__ w2np, short* __restrict__ uvp,
    const int* __restrict__ rows, int* __restrict__ counts)
{
  int b = blockIdx.x;
  if (b < 6) {
    int layer = b;
    const float* src = (layer < 5) ? (eW2 + layer * 64 * 64) : deW2;
    short* dst = w2p + layer * 8192;
    for (int t = threadIdx.x; t < 4096; t += 256) {
      int j = t & 7, n16 = (t >> 3) & 15, quad = (t >> 7) & 3, nt = (t >> 9) & 3,
          s = (t >> 11) & 1;
      float val = src[(s * 32 + quad * 8 + j) * 64 + nt * 16 + n16];
      short hi = f2bf_s(val);
      short lo = f2bf_s(val - bf_s2f(hi));
      int base = ((s * 4 + nt) * 4 + quad) * 128 + n16 * 8 + j;
      dst[base] = hi;
      dst[base + 4096] = lo;
    }
  } else if (b < 406) {
    int g = (b - 6) * 256 + threadIdx.x;
    const float* src; short* dst; int t, K;
    if (g < 40960) {                      // nW1, 5 layers, K=128
      int layer = g >> 13;
      t = g & 8191; K = 128;
      src = nW1 + layer * 8192;
      dst = w1p + layer * 16384;
    } else if (g < 61440) {               // nW2, 5 layers, K=64
      int g2 = g - 40960;
      int layer = g2 >> 12; t = g2 & 4095; K = 64;
      src = nW2 + layer * 4096;
      dst = w2np + layer * 8192;
    } else {                              // next-layer eW1 U/V, n=0..4, K=64
      int g3 = g - 61440;
      int n = g3 >> 13;
      int rem = g3 & 8191;
      int uv = rem >> 12; t = rem & 4095; K = 64;
      const float* base = (n < 4) ? (eW1 + (n + 1) * 129 * 64) : deW1;
      src = base + uv * 4096;
      dst = uvp + n * 16384 + uv * 8192;
    }
    int j = t & 7, quad = (t >> 3) & 3, col = (t >> 5) & 63, s = t >> 11;
    float val = src[(s * 32 + quad * 8 + j) * 64 + col];
    short hi = f2bf_s(val);
    short lo = f2bf_s(val - bf_s2f(hi));
    int di = ((s * 64 + col) * 4 + quad) * 8 + j;
    dst[di] = hi;
    dst[di + K * 64] = lo;
  } else {
    int stride = 400 * 256;
    for (int e = (b - 406) * 256 + threadIdx.x; e < N_EDGES; e += stride)
      atomicAdd(&counts[rows[e]], 1);
  }
}

__global__ __launch_bounds__(256) void k_scanA(const int* __restrict__ counts,
                                               int* __restrict__ bsum)
{
  __shared__ int sd[256];
  int t = threadIdx.x;
  int i = blockIdx.x * 256 + t;
  int x = (i < N_NODES) ? counts[i] : 0;
  sd[t] = x; __syncthreads();
  for (int d = 128; d > 0; d >>= 1) { if (t < d) sd[t] += sd[t + d]; __syncthreads(); }
  if (t == 0) bsum[blockIdx.x] = sd[0];
}

__global__ __launch_bounds__(128) void k_scanB(const int* __restrict__ bsum,
                                               int* __restrict__ boffs)
{
  __shared__ int buf[128];
  int t = threadIdx.x;
  int x = (t < NB_SCAN) ? bsum[t] : 0;
  buf[t] = x; __syncthreads();
  for (int d = 1; d < 128; d <<= 1) {
    int y = (t >= d) ? buf[t - d] : 0;
    __syncthreads();
    buf[t] += y;
    __syncthreads();
  }
  if (t < NB_SCAN) boffs[t] = buf[t] - x;   // exclusive block offsets
}

__global__ __launch_bounds__(256) void k_scanC(const int* __restrict__ counts,
                                               const int* __restrict__ boffs,
                                               int* __restrict__ cursor)
{
  __shared__ int buf[256];
  int t = threadIdx.x;
  int i = blockIdx.x * 256 + t;
  int x = (i < N_NODES) ? counts[i] : 0;
  buf[t] = x; __syncthreads();
  for (int d = 1; d < 256; d <<= 1) {
    int y = (t >= d) ? buf[t - d] : 0;
    __syncthreads();
    buf[t] += y;
    __syncthreads();
  }
  if (i < N_NODES) cursor[i] = boffs[blockIdx.x] + buf[t] - x;
}

__global__ __launch_bounds__(256) void k_scatter(
    const int* __restrict__ rows, const int* __restrict__ cols,
    const float* __restrict__ eatt, int* __restrict__ cursor,
    int* __restrict__ srow, int* __restrict__ scol, float* __restrict__ sea)
{
  int stride = gridDim.x * blockDim.x;
  for (int e = blockIdx.x * blockDim.x + threadIdx.x; e < N_EDGES; e += stride) {
    int r = rows[e];
    int pos = atomicAdd(&cursor[r], 1);
    srow[pos] = r;
    scol[pos] = cols[e];
    sea[pos] = eatt[e];
  }
}

// ---------------------------------------------------------------------------
// Fused embedding + layer-0 precompute (one 16-node tile per block) --
// verified round-10 version.
// ---------------------------------------------------------------------------
__global__ __launch_bounds__(256, 2) void k_embed_fused(
    const float* __restrict__ nodes,
    const float* __restrict__ W_emb, const float* __restrict__ b_emb,
    const float* __restrict__ Wg1, const float* __restrict__ bg1,
    const float* __restrict__ Wg2, const float* __restrict__ bg2,
    const float* __restrict__ eW1_0, const float* __restrict__ eb1_0,
    float* __restrict__ h, float* __restrict__ u, float* __restrict__ v,
    float* __restrict__ agg)
{
  const int lane = threadIdx.x & 63;
  const int wv = threadIdx.x >> 6;
  const int n16 = lane & 15;
  const int quad = lane >> 4;
  const int col = wv * 16 + n16;

  short8 W1hi[4], W1lo[4], W2hi[2], W2lo[2], Uhi[2], Ulo[2], Vhi[2], Vlo[2];
#pragma unroll
  for (int s = 0; s < 4; ++s)
    load_bfrag(Wg1, s * 32 + quad * 8, col, W1hi[s], W1lo[s]);
#pragma unroll
  for (int s = 0; s < 2; ++s) {
    load_bfrag(Wg2, s * 32 + quad * 8, col, W2hi[s], W2lo[s]);
    load_bfrag(eW1_0, s * 32 + quad * 8, col, Uhi[s], Ulo[s]);
    load_bfrag(eW1_0 + 64 * 64, s * 32 + quad * 8, col, Vhi[s], Vlo[s]);
  }
  float bg1v = bg1[col], bg2v = bg2[col], ebv = eb1_0[col];
  float w0 = W_emb[0 * 64 + lane], w1 = W_emb[1 * 64 + lane],
        w2 = W_emb[2 * 64 + lane], w3 = W_emb[3 * 64 + lane],
        w4 = W_emb[4 * 64 + lane];
  float bev = b_emb[lane];

  __shared__ float Ta[128 * 17];
  __shared__ float Tt[64 * 17];
  __shared__ float Th[64 * 17];
  __shared__ float Tu[64 * 17];
  __shared__ float Tv[64 * 17];

  int n0 = blockIdx.x * 16;
#pragma unroll
  for (int e4 = 0; e4 < 4; ++e4) {
    int e = wv * 4 + e4;
    int n = min(n0 + e, N_NODES - 1);
    float x0 = nodes[n * 5 + 0], x1 = nodes[n * 5 + 1],
          x2 = nodes[n * 5 + 2], x3 = nodes[n * 5 + 3],
          x4 = nodes[n * 5 + 4];
    float base = bev + x4 * w4;
    float sv = x0 * w0 + x1 * w1 + x2 * w2 + x3 * w3;
    Ta[lane * 17 + e] = base + sv;
    Ta[(64 + lane) * 17 + e] = base - sv;
  }
  __syncthreads();

  f32x4 a1 = {};
#pragma unroll
  for (int s = 0; s < 4; ++s) {
    short8 ahi, alo;
    load_afrag(Ta, s, quad, n16, ahi, alo);
    a1 = mfma3(ahi, alo, W1hi[s], W1lo[s], a1);
  }
#pragma unroll
  for (int r = 0; r < 4; ++r)
    Tt[col * 17 + quad * 4 + r] = silu_f(a1[r] + bg1v);
  __syncthreads();

  f32x4 a2 = {};
#pragma unroll
  for (int s = 0; s < 2; ++s) {
    short8 ahi, alo;
    load_afrag(Tt, s, quad, n16, ahi, alo);
    a2 = mfma3(ahi, alo, W2hi[s], W2lo[s], a2);
  }
#pragma unroll
  for (int r = 0; r < 4; ++r)
    Th[col * 17 + quad * 4 + r] = a2[r] + bg2v;
  __syncthreads();

  f32x4 aU = {}, aV = {};
#pragma unroll
  for (int s = 0; s < 2; ++s) {
    short8 ahi, alo;
    load_afrag(Th, s, quad, n16, ahi, alo);
    aU = mfma3(ahi, alo, Uhi[s], Ulo[s], aU);
    aV = mfma3(ahi, alo, Vhi[s], Vlo[s], aV);
  }
#pragma unroll
  for (int r = 0; r < 4; ++r) {
    Tu[col * 17 + quad * 4 + r] = aU[r] + ebv;
    Tv[col * 17 + quad * 4 + r] = aV[r];
  }
  __syncthreads();

#pragma unroll
  for (int e4 = 0; e4 < 4; ++e4) {
    int e = wv * 4 + e4;
    int n = n0 + e;
    if (n < N_NODES) {
      h[n * 64 + lane] = Th[lane * 17 + e];
      u[n * 64 + lane] = Tu[lane * 17 + e];
      v[n * 64 + lane] = Tv[lane * 17 + e];
      agg[n * 64 + lane] = 0.f;
    }
  }
}

// ---------------------------------------------------------------------------
// Fused MFMA node kernel, TWO 16-node tiles per block, phase-local table
// fragments, aliased LDS -- verified round-10 version (best known).
// ---------------------------------------------------------------------------
__global__ __launch_bounds__(256, 4) void k_postfused(
    float* __restrict__ h, float* __restrict__ agg,
    const short* __restrict__ w1t, const float* __restrict__ nb1,
    const short* __restrict__ w2t, const float* __restrict__ nb2,
    const short* __restrict__ uvt, const float* __restrict__ eb1n,
    float* __restrict__ u, float* __restrict__ v)
{
  const int lane = threadIdx.x & 63;
  const int wv = threadIdx.x >> 6;
  const int n16 = lane & 15;
  const int quad = lane >> 4;
  const int col = wv * 16 + n16;

  const short8* W1T = reinterpret_cast<const short8*>(w1t);   // K=128: lo at +1024
  const short8* W2T = reinterpret_cast<const short8*>(w2t);   // K=64:  lo at +512
  const short8* UT  = reinterpret_cast<const short8*>(uvt);
  const short8* VT  = reinterpret_cast<const short8*>(uvt + 8192);

  float b1 = nb1[col], b2 = nb2[col], ebv = eb1n[col];

  __shared__ float LA[2][128 * 17];   // Ta -> {Th | Tu}
  __shared__ float LB[2][64 * 17];    // Tt -> Tv

  int t0 = blockIdx.x * 2;
  // P0: load [h|agg]
#pragma unroll
  for (int q = 0; q < 2; ++q) {
    int n0 = (t0 + q) * 16;
#pragma unroll
    for (int e4 = 0; e4 < 4; ++e4) {
      int e = wv * 4 + e4;
      int n = min(n0 + e, N_NODES - 1);
      LA[q][lane * 17 + e] = h[n * 64 + lane];
      LA[q][(64 + lane) * 17 + e] = agg[n * 64 + lane];
    }
  }
  __syncthreads();

  // P1: layer 1 (K=128) -> Tt in LB; W1 frags loaded phase-locally
  {
    short8 W1hi[4], W1lo[4];
#pragma unroll
    for (int s = 0; s < 4; ++s) {
      int idx = (s * 64 + col) * 4 + quad;
      W1hi[s] = W1T[idx];
      W1lo[s] = W1T[idx + 1024];
    }
    f32x4 a1[2] = {};
#pragma unroll
    for (int q = 0; q < 2; ++q)
#pragma unroll
      for (int s = 0; s < 4; ++s) {
        short8 ahi, alo;
        load_afrag(LA[q], s, quad, n16, ahi, alo);
        a1[q] = mfma3(ahi, alo, W1hi[s], W1lo[s], a1[q]);
      }
#pragma unroll
    for (int q = 0; q < 2; ++q)
#pragma unroll
      for (int r = 0; r < 4; ++r)
        LB[q][col * 17 + quad * 4 + r] = silu_f(a1[q][r] + b1);
  }
  __syncthreads();

  // P2: layer 2 (K=64) -> Th into LA[0:1088)
  {
    short8 W2hi[2], W2lo[2];
#pragma unroll
    for (int s = 0; s < 2; ++s) {
      int idx = (s * 64 + col) * 4 + quad;
      W2hi[s] = W2T[idx];
      W2lo[s] = W2T[idx + 512];
    }
    f32x4 a2[2] = {};
#pragma unroll
    for (int q = 0; q < 2; ++q)
#pragma unroll
      for (int s = 0; s < 2; ++s) {
        short8 ahi, alo;
        load_afrag(LB[q], s, quad, n16, ahi, alo);
        a2[q] = mfma3(ahi, alo, W2hi[s], W2lo[s], a2[q]);
      }
#pragma unroll
    for (int q = 0; q < 2; ++q)
#pragma unroll
      for (int r = 0; r < 4; ++r)
        LA[q][col * 17 + quad * 4 + r] = a2[q][r] + b2;
  }
  __syncthreads();

  // P3: next-layer pre (K=64): read Th (LA[0:1088)), write Tu (LA[1088:)),
  //     Tv (LB; Tt dead)
  {
    short8 Uhi[2], Ulo[2], Vhi[2], Vlo[2];
#pragma unroll
    for (int s = 0; s < 2; ++s) {
      int idx = (s * 64 + col) * 4 + quad;
      Uhi[s] = UT[idx];
      Ulo[s] = UT[idx + 512];
      Vhi[s] = VT[idx];
      Vlo[s] = VT[idx + 512];
    }
    f32x4 aU[2] = {}, aV[2] = {};
#pragma unroll
    for (int q = 0; q < 2; ++q)
#pragma unroll
      for (int s = 0; s < 2; ++s) {
        short8 ahi, alo;
        load_afrag(LA[q], s, quad, n16, ahi, alo);
        aU[q] = mfma3(ahi, alo, Uhi[s], Ulo[s], aU[q]);
        aV[q] = mfma3(ahi, alo, Vhi[s], Vlo[s], aV[q]);
      }
#pragma unroll
    for (int q = 0; q < 2; ++q)
#pragma unroll
      for (int r = 0; r < 4; ++r) {
        LA[q][1088 + col * 17 + quad * 4 + r] = aU[q][r] + ebv;
        LB[q][col * 17 + quad * 4 + r] = aV[q][r];
      }
  }
  __syncthreads();

  // P4: coalesced stores + agg zero
#pragma unroll
  for (int q = 0; q < 2; ++q) {
    int n0 = (t0 + q) * 16;
#pragma unroll
    for (int e4 = 0; e4 < 4; ++e4) {
      int e = wv * 4 + e4;
      int n = n0 + e;
      if (n < N_NODES) {
        h[n * 64 + lane] = LA[q][lane * 17 + e];
        u[n * 64 + lane] = LA[q][1088 + lane * 17 + e];
        v[n * 64 + lane] = LB[q][lane * 17 + e];
        agg[n * 64 + lane] = 0.f;
      }
    }
  }
}

// ---------------------------------------------------------------------------
// Fused edge kernel over SORTED edges, TPW=2, lane-local A-fragments,
// W2 table + wea in LDS (verified round 9/10). Round-13: 512-thread blocks
// (8 waves) -> half the per-block prologues per dispatch; same 32 waves/CU
// (LDS 16.9 KB -> 4 blocks/CU x 8 waves). Epilogue restored to the exact
// round-10 form. Tail waves (tile0 >= EDGE_TILES) guarded.
// ---------------------------------------------------------------------------
__global__ __launch_bounds__(512, 8) void k_edge(
    const float* __restrict__ u, const float* __restrict__ v,
    const int* __restrict__ srow, const int* __restrict__ scol,
    const float* __restrict__ sea,
    const float* __restrict__ wea,
    const short* __restrict__ w2p, const float* __restrict__ eb2,
    float* __restrict__ agg)
{
  const int lane = threadIdx.x & 63;
  const int wv = threadIdx.x >> 6;       // 0..7
  const int n16 = lane & 15;
  const int quad = lane >> 4;

  __shared__ short Wlds[8192];     // hi[4096] | lo[4096], k_prep frag order
  __shared__ float weqlds[64];

  // cooperative load: 16 KB W table + 256 B wea, once per block
  {
    const int4* s4 = reinterpret_cast<const int4*>(w2p);
    int4* d4 = reinterpret_cast<int4*>(Wlds);
    for (int i = threadIdx.x; i < 1024; i += 512) d4[i] = s4[i];
    if (threadIdx.x < 64) weqlds[threadIdx.x] = wea[threadIdx.x];
  }
  __syncthreads();

  const short8* WL = reinterpret_cast<const short8*>(Wlds);

  float b2v[4];
#pragma unroll
  for (int nt = 0; nt < 4; ++nt) b2v[nt] = eb2[nt * 16 + n16];

  const int wid = blockIdx.x * 8 + wv;
  const int tile0 = wid * TPW;

  int cur_row = -1;
  bool first_atomic = true;
  float asum[4] = {0.f, 0.f, 0.f, 0.f};

  auto reduce_pick = [&](float a0, float a1, float a2, float a3) -> float {
    a0 += __shfl_xor(a0, 16); a0 += __shfl_xor(a0, 32);
    a1 += __shfl_xor(a1, 16); a1 += __shfl_xor(a1, 32);
    a2 += __shfl_xor(a2, 16); a2 += __shfl_xor(a2, 32);
    a3 += __shfl_xor(a3, 16); a3 += __shfl_xor(a3, 32);
    float o = a0;
    o = (quad == 1) ? a1 : o;
    o = (quad == 2) ? a2 : o;
    o = (quad == 3) ? a3 : o;
    return o;
  };

  auto epilogue = [&](int r16a, f32x4 (&acc)[4]) {
    float ev[4][4];
#pragma unroll
    for (int reg = 0; reg < 4; ++reg)
#pragma unroll
      for (int nt = 0; nt < 4; ++nt)
        ev[reg][nt] = silu_f(acc[nt][reg] + b2v[nt]);

    int rup = __shfl_up(r16a, 1);
    bool nf = (lane < 16) && ((lane == 0) ? (r16a != cur_row) : (r16a != rup));
    unsigned mask = (unsigned)(__ballot(nf) & 0xFFFFull);

    int s = 0;
    while (s < 16) {
      if ((mask >> s) & 1u) {
        if (cur_row >= 0) {
          float o = reduce_pick(asum[0], asum[1], asum[2], asum[3]);
          if (first_atomic) { unsafeAtomicAdd(&agg[cur_row * 64 + lane], o); first_atomic = false; }
          else agg[cur_row * 64 + lane] = o;
        }
        asum[0] = asum[1] = asum[2] = asum[3] = 0.f;
        cur_row = __shfl(r16a, s);
      }
      unsigned rem = mask & ~((2u << s) - 1u);
      int e = rem ? (__ffs(rem) - 1) : 16;
#pragma unroll
      for (int reg = 0; reg < 4; ++reg) {
        int m = quad * 4 + reg;
        bool in = (m >= s) && (m < e);
        asum[0] += in ? ev[reg][0] : 0.f;
        asum[1] += in ? ev[reg][1] : 0.f;
        asum[2] += in ? ev[reg][2] : 0.f;
        asum[3] += in ? ev[reg][3] : 0.f;
      }
      s = e;
    }
  };

  for (int t = 0; t < TPW; ++t) {
    if (tile0 + t >= EDGE_TILES) break;    // tail waves (block 1562, wv>=4)
    int e0 = (tile0 + t) * 16;
    int r16 = srow[e0 + n16];
    int c16 = scol[e0 + n16];
    float ea = sea[e0 + n16];

    // gather this lane's own 16 u/v values (u has eb1 folded in)
    float4 uu[4], vv[4];
    {
      const float* ub = u + r16 * 64 + quad * 8;
      const float* vb = v + c16 * 64 + quad * 8;
      uu[0] = *reinterpret_cast<const float4*>(ub);
      uu[1] = *reinterpret_cast<const float4*>(ub + 4);
      uu[2] = *reinterpret_cast<const float4*>(ub + 32);
      uu[3] = *reinterpret_cast<const float4*>(ub + 36);
      vv[0] = *reinterpret_cast<const float4*>(vb);
      vv[1] = *reinterpret_cast<const float4*>(vb + 4);
      vv[2] = *reinterpret_cast<const float4*>(vb + 32);
      vv[3] = *reinterpret_cast<const float4*>(vb + 36);
    }

    // silu + hi/lo bf16 split; weq read from LDS per 4-k group (broadcast)
    short8 ahi[2], alo[2];
#pragma unroll
    for (int g = 0; g < 4; ++g) {
      int base = (g < 2) ? (quad * 8 + g * 4) : (32 + quad * 8 + (g - 2) * 4);
      float4 wq = *reinterpret_cast<const float4*>(&weqlds[base]);
      const float* uf = reinterpret_cast<const float*>(&uu[g]);
      const float* vf = reinterpret_cast<const float*>(&vv[g]);
      const float* wf = reinterpret_cast<const float*>(&wq);
#pragma unroll
      for (int j = 0; j < 4; ++j) {
        int k = g * 4 + j;
        float tv = silu_f(uf[j] + vf[j] + ea * wf[j]);
        short hi = f2bf_s(tv);
        ahi[k >> 3][k & 7] = hi;
        alo[k >> 3][k & 7] = f2bf_s(tv - bf_s2f(hi));
      }
    }

    // MFMA: W fragments streamed from LDS just-in-time
    f32x4 acc[4] = {};
#pragma unroll
    for (int s = 0; s < 2; ++s)
#pragma unroll
      for (int nt = 0; nt < 4; ++nt) {
        short8 whi = WL[((s * 4 + nt) * 4 + quad) * 16 + n16];
        short8 wlo = WL[((s * 4 + nt) * 4 + quad) * 16 + n16 + 512];
        acc[nt] = __builtin_amdgcn_mfma_f32_16x16x32_bf16(ahi[s], whi, acc[nt], 0, 0, 0);
        acc[nt] = __builtin_amdgcn_mfma_f32_16x16x32_bf16(ahi[s], wlo, acc[nt], 0, 0, 0);
        acc[nt] = __builtin_amdgcn_mfma_f32_16x16x32_bf16(alo[s], whi, acc[nt], 0, 0, 0);
      }

    epilogue(r16, acc);
  }

  // final flush: row may continue into the next wave's range -> atomic
  if (cur_row >= 0) {
    float o = reduce_pick(asum[0], asum[1], asum[2], asum[3]);
    unsafeAtomicAdd(&agg[cur_row * 64 + lane], o);
  }
}

// ---------------------------------------------------------------------------
// Final node MLP (MFMA): out = silu([h|agg]@dnW1 + dnb1) @ dnW2 + dnb2, (N,4)
// ---------------------------------------------------------------------------
__global__ __launch_bounds__(256, 2) void k_final_mfma(
    const float* __restrict__ h, const float* __restrict__ agg,
    const float* __restrict__ dnW1, const float* __restrict__ dnb1,
    const float* __restrict__ dnW2, const float* __restrict__ dnb2,
    float* __restrict__ out)
{
  const int lane = threadIdx.x & 63;
  const int wv = threadIdx.x >> 6;
  const int n16 = lane & 15;
  const int quad = lane >> 4;
  const int col = wv * 16 + n16;

  short8 W1hi[4], W1lo[4];
#pragma unroll
  for (int s = 0; s < 4; ++s)
    load_bfrag(dnW1, s * 32 + quad * 8, col, W1hi[s], W1lo[s]);
  float b1 = dnb1[col];

  __shared__ float Ta[128 * 17];
  __shared__ float Tt[64 * 17];
  __shared__ float W2s[256];
  __shared__ float Tp[4][64];

  W2s[threadIdx.x] = dnW2[threadIdx.x];   // 64x4 = 256 floats

  int n0 = blockIdx.x * 16;
#pragma unroll
  for (int e4 = 0; e4 < 4; ++e4) {
    int e = wv * 4 + e4;
    int n = min(n0 + e, N_NODES - 1);
    Ta[lane * 17 + e] = h[n * 64 + lane];
    Ta[(64 + lane) * 17 + e] = agg[n * 64 + lane];
  }
  __syncthreads();

  f32x4 a1 = {};
#pragma unroll
  for (int s = 0; s < 4; ++s) {
    short8 ahi, alo;
    load_afrag(Ta, s, quad, n16, ahi, alo);
    a1 = mfma3(ahi, alo, W1hi[s], W1lo[s], a1);
  }
#pragma unroll
  for (int r = 0; r < 4; ++r)
    Tt[col * 17 + quad * 4 + r] = silu_f(a1[r] + b1);
  __syncthreads();

  int m = lane >> 2, c = lane & 3;
  float p = 0.f;
#pragma unroll
  for (int kk = 0; kk < 16; ++kk) {
    int k = wv * 16 + kk;
    p += Tt[k * 17 + m] * W2s[k * 4 + c];
  }
  Tp[wv][lane] = p;
  __syncthreads();

  if (threadIdx.x < 64) {
    int n = n0 + (threadIdx.x >> 2);
    if (n < N_NODES) {
      float o = Tp[0][threadIdx.x] + Tp[1][threadIdx.x] +
                Tp[2][threadIdx.x] + Tp[3][threadIdx.x] + dnb2[threadIdx.x & 3];
      out[n * 4 + (threadIdx.x & 3)] = o;
    }
  }
}

extern "C" void kernel_launch(void* const* d_in, const int* in_sizes, int n_in,
                              void* d_out, int out_size, void* d_ws, size_t ws_size,
                              hipStream_t stream)
{
  const float* nodes = (const float*)d_in[0];
  const int*   edges = (const int*)d_in[1];
  const float* eatt  = (const float*)d_in[2];
  const float* W_emb = (const float*)d_in[3];
  const float* b_emb = (const float*)d_in[4];
  const float* Wg1   = (const float*)d_in[5];
  const float* bg1   = (const float*)d_in[6];
  const float* Wg2   = (const float*)d_in[7];
  const float* bg2   = (const float*)d_in[8];
  const float* eW1   = (const float*)d_in[9];
  const float* eb1   = (const float*)d_in[10];
  const float* eW2   = (const float*)d_in[11];
  const float* eb2   = (const float*)d_in[12];
  const float* nW1   = (const float*)d_in[13];
  const float* nb1   = (const float*)d_in[14];
  const float* nW2   = (const float*)d_in[15];
  const float* nb2   = (const float*)d_in[16];
  const float* deW1  = (const float*)d_in[17];
  const float* deb1  = (const float*)d_in[18];
  const float* deW2  = (const float*)d_in[19];
  const float* deb2  = (const float*)d_in[20];
  const float* dnW1  = (const float*)d_in[21];
  const float* dnb1  = (const float*)d_in[22];
  const float* dnW2  = (const float*)d_in[23];
  const float* dnb2  = (const float*)d_in[24];
  float* out = (float*)d_out;

  float* h   = (float*)d_ws;
  float* u   = h + N_NODES * 64;
  float* v   = u + N_NODES * 64;
  float* agg = v + N_NODES * 64;
  int* counts = (int*)(agg + N_NODES * 64);
  int* cursor = counts + N_NODES;
  int* bsum   = cursor + N_NODES;
  int* boffs  = bsum + 128;
  int* srow   = boffs + 128;
  int* scol   = srow + N_EDGES;
  float* sea  = (float*)(scol + N_EDGES);
  short* w2p  = (short*)(sea + N_EDGES);   // 6 x 8192 shorts (edge W2 tables)
  short* w1p  = w2p + 6 * 8192;            // 5 x 16384 shorts (nW1 tables)
  short* w2np = w1p + 5 * 16384;           // 5 x 8192 shorts (nW2 tables)
  short* uvp  = w2np + 5 * 8192;           // 5 x 16384 shorts (U|V tables)

  const int* rows = edges;
  const int* cols = edges + N_EDGES;

  // --- one-time preprocessing (graph static across layers) ---
  hipMemsetAsync(counts, 0, N_NODES * sizeof(int), stream);
  k_prep<<<806, 256, 0, stream>>>(eW2, deW2, w2p, nW1, nW2, eW1, deW1,
                                  w1p, w2np, uvp, rows, counts);
  k_scanA<<<NB_SCAN, 256, 0, stream>>>(counts, bsum);
  k_scanB<<<1, 128, 0, stream>>>(bsum, boffs);
  k_scanC<<<NB_SCAN, 256, 0, stream>>>(counts, boffs, cursor);
  k_scatter<<<400, 256, 0, stream>>>(rows, cols, eatt, cursor, srow, scol, sea);

  // fused embed + layer-0 u/v (eb1 of layer 0 folded into u)
  k_embed_fused<<<NODE_TILES, 256, 0, stream>>>(nodes, W_emb, b_emb, Wg1, bg1,
                                                Wg2, bg2, eW1, eb1, h, u, v, agg);

  for (int i = 0; i < 5; ++i) {
    k_edge<<<EDGE_BLOCKS512, 512, 0, stream>>>(u, v, srow, scol, sea,
                                               eW1 + i * 129 * 64 + 128 * 64,
                                               w2p + i * 8192, eb2 + i * 64, agg);
    const float* eb1next = (i < 4) ? (eb1 + (i + 1) * 64) : deb1;
    k_postfused<<<NODE_BLOCKS2, 256, 0, stream>>>(h, agg,
                                                  w1p + i * 16384, nb1 + i * 64,
                                                  w2np + i * 8192, nb2 + i * 64,
                                                  uvp + i * 16384, eb1next, u, v);
  }
  // decoder GCL edge pass
  k_edge<<<EDGE_BLOCKS512, 512, 0, stream>>>(u, v, srow, scol, sea, deW1 + 128 * 64,
                                             w2p + 5 * 8192, deb2, agg);
  k_final_mfma<<<NODE_TILES, 256, 0, stream>>>(h, agg, dnW1, dnb1, dnW2, dnb2, out);
}

// Round 14
// 429.401 us; speedup vs baseline: 1.0457x; 1.0457x over previous
//
#include <hip/hip_runtime.h>
#include <hip/hip_bf16.h>

#define N_NODES 25000
#define N_EDGES 400000
#define NB_SCAN ((N_NODES + 255) / 256)   // 98
#define EDGE_TILES (N_EDGES / 16)          // 25000
#define TPW 2                              // tiles per wave (edge kernel)
#define EDGE_WAVES (EDGE_TILES / TPW)      // 12500 exact
#define EDGE_BLOCKS (EDGE_WAVES / 4)       // 3125 exact
#define NODE_TILES ((N_NODES + 15) / 16)   // 1563
#define NODE_BLOCKS2 ((NODE_TILES + 1) / 2) // 782 (2 tiles/block)

typedef __attribute__((ext_vector_type(8))) short short8;
typedef __attribute__((ext_vector_type(4))) float f32x4;

// fast silu: v_rcp_f32 (<=1 ulp) instead of full-precision divide sequence
__device__ __forceinline__ float silu_f(float x) {
  return x * __builtin_amdgcn_rcpf(1.0f + __expf(-x));
}

__device__ __forceinline__ short f2bf_s(float x) {
  __hip_bfloat16 h = __float2bfloat16(x);
  return *reinterpret_cast<short*>(&h);
}
__device__ __forceinline__ float bf_s2f(short s) {
  __hip_bfloat16 h = *reinterpret_cast<__hip_bfloat16*>(&s);
  return __bfloat162float(h);
}

// --- shared MFMA helpers (layout identical to the verified k_edge path) ----
// A-frag from LDS tile T[k][m] (stride 17): A[m=n16][k=s*32+quad*8+j]
__device__ __forceinline__ void load_afrag(const float* T, int s, int quad, int n16,
                                           short8& ahi, short8& alo) {
#pragma unroll
  for (int j = 0; j < 8; ++j) {
    float tv = T[(s * 32 + quad * 8 + j) * 17 + n16];
    short hi = f2bf_s(tv);
    ahi[j] = hi;
    alo[j] = f2bf_s(tv - bf_s2f(hi));
  }
}
// B-frag from global W[k][n] (row-major, 64 cols): B[k=k0+j][n=col]
__device__ __forceinline__ void load_bfrag(const float* __restrict__ W, int k0, int col,
                                           short8& bhi, short8& blo) {
#pragma unroll
  for (int j = 0; j < 8; ++j) {
    float w = W[(k0 + j) * 64 + col];
    short hi = f2bf_s(w);
    bhi[j] = hi;
    blo[j] = f2bf_s(w - bf_s2f(hi));
  }
}
// split-bf16 3-product ~fp32 MFMA
__device__ __forceinline__ f32x4 mfma3(short8 ahi, short8 alo, short8 bhi, short8 blo,
                                       f32x4 acc) {
  acc = __builtin_amdgcn_mfma_f32_16x16x32_bf16(ahi, bhi, acc, 0, 0, 0);
  acc = __builtin_amdgcn_mfma_f32_16x16x32_bf16(ahi, blo, acc, 0, 0, 0);
  acc = __builtin_amdgcn_mfma_f32_16x16x32_bf16(alo, bhi, acc, 0, 0, 0);
  return acc;
}

// ---------------------------------------------------------------------------
// Edge preprocessing: counting sort by destination row (once per launch).
// ---------------------------------------------------------------------------
__global__ __launch_bounds__(256) void k_hist(const int* __restrict__ rows,
                                              int* __restrict__ counts)
{
  int stride = gridDim.x * blockDim.x;
  for (int e = blockIdx.x * blockDim.x + threadIdx.x; e < N_EDGES; e += stride)
    atomicAdd(&counts[rows[e]], 1);
}

__global__ __launch_bounds__(256) void k_scanA(const int* __restrict__ counts,
                                               int* __restrict__ bsum)
{
  __shared__ int sd[256];
  int t = threadIdx.x;
  int i = blockIdx.x * 256 + t;
  int x = (i < N_NODES) ? counts[i] : 0;
  sd[t] = x; __syncthreads();
  for (int d = 128; d > 0; d >>= 1) { if (t < d) sd[t] += sd[t + d]; __syncthreads(); }
  if (t == 0) bsum[blockIdx.x] = sd[0];
}

__global__ __launch_bounds__(128) void k_scanB(const int* __restrict__ bsum,
                                               int* __restrict__ boffs)
{
  __shared__ int buf[128];
  int t = threadIdx.x;
  int x = (t < NB_SCAN) ? bsum[t] : 0;
  buf[t] = x; __syncthreads();
  for (int d = 1; d < 128; d <<= 1) {
    int y = (t >= d) ? buf[t - d] : 0;
    __syncthreads();
    buf[t] += y;
    __syncthreads();
  }
  if (t < NB_SCAN) boffs[t] = buf[t] - x;   // exclusive block offsets
}

__global__ __launch_bounds__(256) void k_scanC(const int* __restrict__ counts,
                                               const int* __restrict__ boffs,
                                               int* __restrict__ cursor)
{
  __shared__ int buf[256];
  int t = threadIdx.x;
  int i = blockIdx.x * 256 + t;
  int x = (i < N_NODES) ? counts[i] : 0;
  buf[t] = x; __syncthreads();
  for (int d = 1; d < 256; d <<= 1) {
    int y = (t >= d) ? buf[t - d] : 0;
    __syncthreads();
    buf[t] += y;
    __syncthreads();
  }
  if (i < N_NODES) cursor[i] = boffs[blockIdx.x] + buf[t] - x;
}

__global__ __launch_bounds__(256) void k_scatter(
    const int* __restrict__ rows, const int* __restrict__ cols,
    const float* __restrict__ eatt, int* __restrict__ cursor,
    int* __restrict__ srow, int* __restrict__ scol, float* __restrict__ sea)
{
  int stride = gridDim.x * blockDim.x;
  for (int e = blockIdx.x * blockDim.x + threadIdx.x; e < N_EDGES; e += stride) {
    int r = rows[e];
    int pos = atomicAdd(&cursor[r], 1);
    srow[pos] = r;
    scol[pos] = cols[e];
    sea[pos] = eatt[e];
  }
}

// ---------------------------------------------------------------------------
// W2 fragment prep: split each layer's eW2 (64x64 f32) into hi/lo bf16 in
// EXACT k_edge fragment order so k_edge reads short8 frags directly.
// blockIdx.x = layer (0..4 = eW2[i], 5 = deW2).
// ---------------------------------------------------------------------------
__global__ __launch_bounds__(256) void k_w2prep(const float* __restrict__ eW2,
                                                const float* __restrict__ deW2,
                                                short* __restrict__ w2p)
{
  int layer = blockIdx.x;
  const float* src = (layer < 5) ? (eW2 + layer * 64 * 64) : deW2;
  short* dst = w2p + layer * 8192;
  for (int t = threadIdx.x; t < 4096; t += 256) {
    int j = t & 7, n16 = (t >> 3) & 15, quad = (t >> 7) & 3, nt = (t >> 9) & 3,
        s = (t >> 11) & 1;
    float val = src[(s * 32 + quad * 8 + j) * 64 + nt * 16 + n16];
    short hi = f2bf_s(val);
    short lo = f2bf_s(val - bf_s2f(hi));
    int base = ((s * 4 + nt) * 4 + quad) * 128 + n16 * 8 + j;
    dst[base] = hi;
    dst[base + 4096] = lo;
  }
}

// ---------------------------------------------------------------------------
// Node-weight fragment prep (once per launch): split nW1 (K=128), nW2 (K=64),
// and next-layer eW1 U/V (K=64) for all 5 GCL iterations into frag-ordered
// bf16 hi/lo tables so k_postfused loads short8 frags directly.
// dst short index: ((s*64+col)*4+quad)*8 + j ; hi at base, lo at base+K*64.
// Values bitwise-identical to load_bfrag. 102400 elems = 400 blocks exact.
// ---------------------------------------------------------------------------
__global__ __launch_bounds__(256) void k_nodeprep(
    const float* __restrict__ nW1, const float* __restrict__ nW2,
    const float* __restrict__ eW1, const float* __restrict__ deW1,
    short* __restrict__ w1p, short* __restrict__ w2np, short* __restrict__ uvp)
{
  int g = blockIdx.x * 256 + threadIdx.x;
  const float* src; short* dst; int t, K;
  if (g < 40960) {                      // nW1, 5 layers, K=128
    int layer = g >> 13;
    t = g & 8191; K = 128;
    src = nW1 + layer * 8192;
    dst = w1p + layer * 16384;
  } else if (g < 61440) {               // nW2, 5 layers, K=64
    int g2 = g - 40960;
    int layer = g2 >> 12; t = g2 & 4095; K = 64;
    src = nW2 + layer * 4096;
    dst = w2np + layer * 8192;
  } else {                              // next-layer eW1 U/V, n=0..4, K=64
    int g3 = g - 61440;
    int n = g3 >> 13;
    int rem = g3 & 8191;
    int uv = rem >> 12; t = rem & 4095; K = 64;
    const float* base = (n < 4) ? (eW1 + (n + 1) * 129 * 64) : deW1;
    src = base + uv * 4096;
    dst = uvp + n * 16384 + uv * 8192;
  }
  int j = t & 7, quad = (t >> 3) & 3, col = (t >> 5) & 63, s = t >> 11;
  float val = src[(s * 32 + quad * 8 + j) * 64 + col];
  short hi = f2bf_s(val);
  short lo = f2bf_s(val - bf_s2f(hi));
  int di = ((s * 64 + col) * 4 + quad) * 8 + j;
  dst[di] = hi;
  dst[di + K * 64] = lo;
}

// ---------------------------------------------------------------------------
// Fused embedding + layer-0 precompute (one 16-node tile per block).
// ---------------------------------------------------------------------------
__global__ __launch_bounds__(256, 2) void k_embed_fused(
    const float* __restrict__ nodes,
    const float* __restrict__ W_emb, const float* __restrict__ b_emb,
    const float* __restrict__ Wg1, const float* __restrict__ bg1,
    const float* __restrict__ Wg2, const float* __restrict__ bg2,
    const float* __restrict__ eW1_0, const float* __restrict__ eb1_0,
    float* __restrict__ h, float* __restrict__ u, float* __restrict__ v,
    float* __restrict__ agg)
{
  const int lane = threadIdx.x & 63;
  const int wv = threadIdx.x >> 6;
  const int n16 = lane & 15;
  const int quad = lane >> 4;
  const int col = wv * 16 + n16;

  short8 W1hi[4], W1lo[4], W2hi[2], W2lo[2], Uhi[2], Ulo[2], Vhi[2], Vlo[2];
#pragma unroll
  for (int s = 0; s < 4; ++s)
    load_bfrag(Wg1, s * 32 + quad * 8, col, W1hi[s], W1lo[s]);
#pragma unroll
  for (int s = 0; s < 2; ++s) {
    load_bfrag(Wg2, s * 32 + quad * 8, col, W2hi[s], W2lo[s]);
    load_bfrag(eW1_0, s * 32 + quad * 8, col, Uhi[s], Ulo[s]);
    load_bfrag(eW1_0 + 64 * 64, s * 32 + quad * 8, col, Vhi[s], Vlo[s]);
  }
  float bg1v = bg1[col], bg2v = bg2[col], ebv = eb1_0[col];
  float w0 = W_emb[0 * 64 + lane], w1 = W_emb[1 * 64 + lane],
        w2 = W_emb[2 * 64 + lane], w3 = W_emb[3 * 64 + lane],
        w4 = W_emb[4 * 64 + lane];
  float bev = b_emb[lane];

  __shared__ float Ta[128 * 17];
  __shared__ float Tt[64 * 17];
  __shared__ float Th[64 * 17];
  __shared__ float Tu[64 * 17];
  __shared__ float Tv[64 * 17];

  int n0 = blockIdx.x * 16;
#pragma unroll
  for (int e4 = 0; e4 < 4; ++e4) {
    int e = wv * 4 + e4;
    int n = min(n0 + e, N_NODES - 1);
    float x0 = nodes[n * 5 + 0], x1 = nodes[n * 5 + 1],
          x2 = nodes[n * 5 + 2], x3 = nodes[n * 5 + 3],
          x4 = nodes[n * 5 + 4];
    float base = bev + x4 * w4;
    float sv = x0 * w0 + x1 * w1 + x2 * w2 + x3 * w3;
    Ta[lane * 17 + e] = base + sv;
    Ta[(64 + lane) * 17 + e] = base - sv;
  }
  __syncthreads();

  f32x4 a1 = {};
#pragma unroll
  for (int s = 0; s < 4; ++s) {
    short8 ahi, alo;
    load_afrag(Ta, s, quad, n16, ahi, alo);
    a1 = mfma3(ahi, alo, W1hi[s], W1lo[s], a1);
  }
#pragma unroll
  for (int r = 0; r < 4; ++r)
    Tt[col * 17 + quad * 4 + r] = silu_f(a1[r] + bg1v);
  __syncthreads();

  f32x4 a2 = {};
#pragma unroll
  for (int s = 0; s < 2; ++s) {
    short8 ahi, alo;
    load_afrag(Tt, s, quad, n16, ahi, alo);
    a2 = mfma3(ahi, alo, W2hi[s], W2lo[s], a2);
  }
#pragma unroll
  for (int r = 0; r < 4; ++r)
    Th[col * 17 + quad * 4 + r] = a2[r] + bg2v;
  __syncthreads();

  f32x4 aU = {}, aV = {};
#pragma unroll
  for (int s = 0; s < 2; ++s) {
    short8 ahi, alo;
    load_afrag(Th, s, quad, n16, ahi, alo);
    aU = mfma3(ahi, alo, Uhi[s], Ulo[s], aU);
    aV = mfma3(ahi, alo, Vhi[s], Vlo[s], aV);
  }
#pragma unroll
  for (int r = 0; r < 4; ++r) {
    Tu[col * 17 + quad * 4 + r] = aU[r] + ebv;
    Tv[col * 17 + quad * 4 + r] = aV[r];
  }
  __syncthreads();

#pragma unroll
  for (int e4 = 0; e4 < 4; ++e4) {
    int e = wv * 4 + e4;
    int n = n0 + e;
    if (n < N_NODES) {
      h[n * 64 + lane] = Th[lane * 17 + e];
      u[n * 64 + lane] = Tu[lane * 17 + e];
      v[n * 64 + lane] = Tv[lane * 17 + e];
      agg[n * 64 + lane] = 0.f;
    }
  }
}

// ---------------------------------------------------------------------------
// Fused MFMA node kernel, TWO 16-node tiles per block (verified round 6
// phase/barrier structure), round-10 OCCUPANCY version:
//   - B-fragments loaded PHASE-LOCALLY as coalesced short8 from the
//     k_nodeprep tables (bitwise-identical values, no f32 loads, no cvt
//     prologue) -> peak live registers drop from 64-held-throughout to
//     ~32-per-phase.
//   - __launch_bounds__(256, 4): target <=128 VGPR -> 4 blocks/CU
//     (LDS 4 x 25.5 KB = 102 KB < 160 KB).
// ---------------------------------------------------------------------------
__global__ __launch_bounds__(256, 4) void k_postfused(
    float* __restrict__ h, float* __restrict__ agg,
    const short* __restrict__ w1t, const float* __restrict__ nb1,
    const short* __restrict__ w2t, const float* __restrict__ nb2,
    const short* __restrict__ uvt, const float* __restrict__ eb1n,
    float* __restrict__ u, float* __restrict__ v)
{
  const int lane = threadIdx.x & 63;
  const int wv = threadIdx.x >> 6;
  const int n16 = lane & 15;
  const int quad = lane >> 4;
  const int col = wv * 16 + n16;

  const short8* W1T = reinterpret_cast<const short8*>(w1t);   // K=128: lo at +1024
  const short8* W2T = reinterpret_cast<const short8*>(w2t);   // K=64:  lo at +512
  const short8* UT  = reinterpret_cast<const short8*>(uvt);
  const short8* VT  = reinterpret_cast<const short8*>(uvt + 8192);

  float b1 = nb1[col], b2 = nb2[col], ebv = eb1n[col];

  __shared__ float LA[2][128 * 17];   // Ta -> {Th | Tu}
  __shared__ float LB[2][64 * 17];    // Tt -> Tv

  int t0 = blockIdx.x * 2;
  // P0: load [h|agg]
#pragma unroll
  for (int q = 0; q < 2; ++q) {
    int n0 = (t0 + q) * 16;
#pragma unroll
    for (int e4 = 0; e4 < 4; ++e4) {
      int e = wv * 4 + e4;
      int n = min(n0 + e, N_NODES - 1);
      LA[q][lane * 17 + e] = h[n * 64 + lane];
      LA[q][(64 + lane) * 17 + e] = agg[n * 64 + lane];
    }
  }
  __syncthreads();

  // P1: layer 1 (K=128) -> Tt in LB. W1 frags loaded phase-locally; the
  // loads fly under the ds_reads of the A-fragments.
  {
    short8 W1hi[4], W1lo[4];
#pragma unroll
    for (int s = 0; s < 4; ++s) {
      int idx = (s * 64 + col) * 4 + quad;
      W1hi[s] = W1T[idx];
      W1lo[s] = W1T[idx + 1024];
    }
    f32x4 a1[2] = {};
#pragma unroll
    for (int q = 0; q < 2; ++q)
#pragma unroll
      for (int s = 0; s < 4; ++s) {
        short8 ahi, alo;
        load_afrag(LA[q], s, quad, n16, ahi, alo);
        a1[q] = mfma3(ahi, alo, W1hi[s], W1lo[s], a1[q]);
      }
#pragma unroll
    for (int q = 0; q < 2; ++q)
#pragma unroll
      for (int r = 0; r < 4; ++r)
        LB[q][col * 17 + quad * 4 + r] = silu_f(a1[q][r] + b1);
  }
  __syncthreads();

  // P2: layer 2 (K=64) -> Th into LA[0:1088)
  {
    short8 W2hi[2], W2lo[2];
#pragma unroll
    for (int s = 0; s < 2; ++s) {
      int idx = (s * 64 + col) * 4 + quad;
      W2hi[s] = W2T[idx];
      W2lo[s] = W2T[idx + 512];
    }
    f32x4 a2[2] = {};
#pragma unroll
    for (int q = 0; q < 2; ++q)
#pragma unroll
      for (int s = 0; s < 2; ++s) {
        short8 ahi, alo;
        load_afrag(LB[q], s, quad, n16, ahi, alo);
        a2[q] = mfma3(ahi, alo, W2hi[s], W2lo[s], a2[q]);
      }
#pragma unroll
    for (int q = 0; q < 2; ++q)
#pragma unroll
      for (int r = 0; r < 4; ++r)
        LA[q][col * 17 + quad * 4 + r] = a2[q][r] + b2;
  }
  __syncthreads();

  // P3: next-layer pre (K=64): read Th (LA[0:1088)), write Tu (LA[1088:)),
  //     Tv (LB; Tt dead)
  {
    short8 Uhi[2], Ulo[2], Vhi[2], Vlo[2];
#pragma unroll
    for (int s = 0; s < 2; ++s) {
      int idx = (s * 64 + col) * 4 + quad;
      Uhi[s] = UT[idx];
      Ulo[s] = UT[idx + 512];
      Vhi[s] = VT[idx];
      Vlo[s] = VT[idx + 512];
    }
    f32x4 aU[2] = {}, aV[2] = {};
#pragma unroll
    for (int q = 0; q < 2; ++q)
#pragma unroll
      for (int s = 0; s < 2; ++s) {
        short8 ahi, alo;
        load_afrag(LA[q], s, quad, n16, ahi, alo);
        aU[q] = mfma3(ahi, alo, Uhi[s], Ulo[s], aU[q]);
        aV[q] = mfma3(ahi, alo, Vhi[s], Vlo[s], aV[q]);
      }
#pragma unroll
    for (int q = 0; q < 2; ++q)
#pragma unroll
      for (int r = 0; r < 4; ++r) {
        LA[q][1088 + col * 17 + quad * 4 + r] = aU[q][r] + ebv;
        LB[q][col * 17 + quad * 4 + r] = aV[q][r];
      }
  }
  __syncthreads();

  // P4: coalesced stores + agg zero
#pragma unroll
  for (int q = 0; q < 2; ++q) {
    int n0 = (t0 + q) * 16;
#pragma unroll
    for (int e4 = 0; e4 < 4; ++e4) {
      int e = wv * 4 + e4;
      int n = n0 + e;
      if (n < N_NODES) {
        h[n * 64 + lane] = LA[q][lane * 17 + e];
        u[n * 64 + lane] = LA[q][1088 + lane * 17 + e];
        v[n * 64 + lane] = LB[q][lane * 17 + e];
        agg[n * 64 + lane] = 0.f;
      }
    }
  }
}

// ---------------------------------------------------------------------------
// Fused edge kernel over SORTED edges, TPW=2, lane-local A-fragments,
// W2 table + wea in LDS, 8 blocks/CU (verified round 9/10).
// ---------------------------------------------------------------------------
__global__ __launch_bounds__(256, 8) void k_edge(
    const float* __restrict__ u, const float* __restrict__ v,
    const int* __restrict__ srow, const int* __restrict__ scol,
    const float* __restrict__ sea,
    const float* __restrict__ wea,
    const short* __restrict__ w2p, const float* __restrict__ eb2,
    float* __restrict__ agg)
{
  const int lane = threadIdx.x & 63;
  const int wv = threadIdx.x >> 6;
  const int n16 = lane & 15;
  const int quad = lane >> 4;

  __shared__ short Wlds[8192];     // hi[4096] | lo[4096], k_w2prep frag order
  __shared__ float weqlds[64];

  // cooperative load: 16 KB W table + 256 B wea, once per block
  {
    const int4* s4 = reinterpret_cast<const int4*>(w2p);
    int4* d4 = reinterpret_cast<int4*>(Wlds);
    for (int i = threadIdx.x; i < 1024; i += 256) d4[i] = s4[i];
    if (threadIdx.x < 64) weqlds[threadIdx.x] = wea[threadIdx.x];
  }
  __syncthreads();

  const short8* WL = reinterpret_cast<const short8*>(Wlds);

  float b2v[4];
#pragma unroll
  for (int nt = 0; nt < 4; ++nt) b2v[nt] = eb2[nt * 16 + n16];

  const int wid = blockIdx.x * 4 + wv;
  const int tile0 = wid * TPW;       // exact: 12500 waves x 2 tiles = 25000

  int cur_row = -1;
  bool first_atomic = true;
  float asum[4] = {0.f, 0.f, 0.f, 0.f};

  auto reduce_pick = [&](float a0, float a1, float a2, float a3) -> float {
    a0 += __shfl_xor(a0, 16); a0 += __shfl_xor(a0, 32);
    a1 += __shfl_xor(a1, 16); a1 += __shfl_xor(a1, 32);
    a2 += __shfl_xor(a2, 16); a2 += __shfl_xor(a2, 32);
    a3 += __shfl_xor(a3, 16); a3 += __shfl_xor(a3, 32);
    float o = a0;
    o = (quad == 1) ? a1 : o;
    o = (quad == 2) ? a2 : o;
    o = (quad == 3) ? a3 : o;
    return o;
  };

  auto epilogue = [&](int r16a, f32x4 (&acc)[4]) {
    float ev[4][4];
#pragma unroll
    for (int reg = 0; reg < 4; ++reg)
#pragma unroll
      for (int nt = 0; nt < 4; ++nt)
        ev[reg][nt] = silu_f(acc[nt][reg] + b2v[nt]);

    int rup = __shfl_up(r16a, 1);
    bool nf = (lane < 16) && ((lane == 0) ? (r16a != cur_row) : (r16a != rup));
    unsigned mask = (unsigned)(__ballot(nf) & 0xFFFFull);

    int s = 0;
    while (s < 16) {
      if ((mask >> s) & 1u) {
        if (cur_row >= 0) {
          float o = reduce_pick(asum[0], asum[1], asum[2], asum[3]);
          if (first_atomic) { unsafeAtomicAdd(&agg[cur_row * 64 + lane], o); first_atomic = false; }
          else agg[cur_row * 64 + lane] = o;
        }
        asum[0] = asum[1] = asum[2] = asum[3] = 0.f;
        cur_row = __shfl(r16a, s);
      }
      unsigned rem = mask & ~((2u << s) - 1u);
      int e = rem ? (__ffs(rem) - 1) : 16;
#pragma unroll
      for (int reg = 0; reg < 4; ++reg) {
        int m = quad * 4 + reg;
        bool in = (m >= s) && (m < e);
        asum[0] += in ? ev[reg][0] : 0.f;
        asum[1] += in ? ev[reg][1] : 0.f;
        asum[2] += in ? ev[reg][2] : 0.f;
        asum[3] += in ? ev[reg][3] : 0.f;
      }
      s = e;
    }
  };

  for (int t = 0; t < TPW; ++t) {
    int e0 = (tile0 + t) * 16;
    int r16 = srow[e0 + n16];
    int c16 = scol[e0 + n16];
    float ea = sea[e0 + n16];

    // gather this lane's own 16 u/v values (u has eb1 folded in)
    float4 uu[4], vv[4];
    {
      const float* ub = u + r16 * 64 + quad * 8;
      const float* vb = v + c16 * 64 + quad * 8;
      uu[0] = *reinterpret_cast<const float4*>(ub);
      uu[1] = *reinterpret_cast<const float4*>(ub + 4);
      uu[2] = *reinterpret_cast<const float4*>(ub + 32);
      uu[3] = *reinterpret_cast<const float4*>(ub + 36);
      vv[0] = *reinterpret_cast<const float4*>(vb);
      vv[1] = *reinterpret_cast<const float4*>(vb + 4);
      vv[2] = *reinterpret_cast<const float4*>(vb + 32);
      vv[3] = *reinterpret_cast<const float4*>(vb + 36);
    }

    // silu + hi/lo bf16 split; weq read from LDS per 4-k group (broadcast)
    short8 ahi[2], alo[2];
#pragma unroll
    for (int g = 0; g < 4; ++g) {
      int base = (g < 2) ? (quad * 8 + g * 4) : (32 + quad * 8 + (g - 2) * 4);
      float4 wq = *reinterpret_cast<const float4*>(&weqlds[base]);
      const float* uf = reinterpret_cast<const float*>(&uu[g]);
      const float* vf = reinterpret_cast<const float*>(&vv[g]);
      const float* wf = reinterpret_cast<const float*>(&wq);
#pragma unroll
      for (int j = 0; j < 4; ++j) {
        int k = g * 4 + j;
        float tv = silu_f(uf[j] + vf[j] + ea * wf[j]);
        short hi = f2bf_s(tv);
        ahi[k >> 3][k & 7] = hi;
        alo[k >> 3][k & 7] = f2bf_s(tv - bf_s2f(hi));
      }
    }

    // MFMA: W fragments streamed from LDS just-in-time
    f32x4 acc[4] = {};
#pragma unroll
    for (int s = 0; s < 2; ++s)
#pragma unroll
      for (int nt = 0; nt < 4; ++nt) {
        short8 whi = WL[((s * 4 + nt) * 4 + quad) * 16 + n16];
        short8 wlo = WL[((s * 4 + nt) * 4 + quad) * 16 + n16 + 512];
        acc[nt] = __builtin_amdgcn_mfma_f32_16x16x32_bf16(ahi[s], whi, acc[nt], 0, 0, 0);
        acc[nt] = __builtin_amdgcn_mfma_f32_16x16x32_bf16(ahi[s], wlo, acc[nt], 0, 0, 0);
        acc[nt] = __builtin_amdgcn_mfma_f32_16x16x32_bf16(alo[s], whi, acc[nt], 0, 0, 0);
      }

    epilogue(r16, acc);
  }

  // final flush: row may continue into the next wave's range -> atomic
  if (cur_row >= 0) {
    float o = reduce_pick(asum[0], asum[1], asum[2], asum[3]);
    unsafeAtomicAdd(&agg[cur_row * 64 + lane], o);
  }
}

// ---------------------------------------------------------------------------
// Final node MLP (MFMA): out = silu([h|agg]@dnW1 + dnb1) @ dnW2 + dnb2, (N,4)
// ---------------------------------------------------------------------------
__global__ __launch_bounds__(256, 2) void k_final_mfma(
    const float* __restrict__ h, const float* __restrict__ agg,
    const float* __restrict__ dnW1, const float* __restrict__ dnb1,
    const float* __restrict__ dnW2, const float* __restrict__ dnb2,
    float* __restrict__ out)
{
  const int lane = threadIdx.x & 63;
  const int wv = threadIdx.x >> 6;
  const int n16 = lane & 15;
  const int quad = lane >> 4;
  const int col = wv * 16 + n16;

  short8 W1hi[4], W1lo[4];
#pragma unroll
  for (int s = 0; s < 4; ++s)
    load_bfrag(dnW1, s * 32 + quad * 8, col, W1hi[s], W1lo[s]);
  float b1 = dnb1[col];

  __shared__ float Ta[128 * 17];
  __shared__ float Tt[64 * 17];
  __shared__ float W2s[256];
  __shared__ float Tp[4][64];

  W2s[threadIdx.x] = dnW2[threadIdx.x];   // 64x4 = 256 floats

  int n0 = blockIdx.x * 16;
#pragma unroll
  for (int e4 = 0; e4 < 4; ++e4) {
    int e = wv * 4 + e4;
    int n = min(n0 + e, N_NODES - 1);
    Ta[lane * 17 + e] = h[n * 64 + lane];
    Ta[(64 + lane) * 17 + e] = agg[n * 64 + lane];
  }
  __syncthreads();

  f32x4 a1 = {};
#pragma unroll
  for (int s = 0; s < 4; ++s) {
    short8 ahi, alo;
    load_afrag(Ta, s, quad, n16, ahi, alo);
    a1 = mfma3(ahi, alo, W1hi[s], W1lo[s], a1);
  }
#pragma unroll
  for (int r = 0; r < 4; ++r)
    Tt[col * 17 + quad * 4 + r] = silu_f(a1[r] + b1);
  __syncthreads();

  int m = lane >> 2, c = lane & 3;
  float p = 0.f;
#pragma unroll
  for (int kk = 0; kk < 16; ++kk) {
    int k = wv * 16 + kk;
    p += Tt[k * 17 + m] * W2s[k * 4 + c];
  }
  Tp[wv][lane] = p;
  __syncthreads();

  if (threadIdx.x < 64) {
    int n = n0 + (threadIdx.x >> 2);
    if (n < N_NODES) {
      float o = Tp[0][threadIdx.x] + Tp[1][threadIdx.x] +
                Tp[2][threadIdx.x] + Tp[3][threadIdx.x] + dnb2[threadIdx.x & 3];
      out[n * 4 + (threadIdx.x & 3)] = o;
    }
  }
}

extern "C" void kernel_launch(void* const* d_in, const int* in_sizes, int n_in,
                              void* d_out, int out_size, void* d_ws, size_t ws_size,
                              hipStream_t stream)
{
  const float* nodes = (const float*)d_in[0];
  const int*   edges = (const int*)d_in[1];
  const float* eatt  = (const float*)d_in[2];
  const float* W_emb = (const float*)d_in[3];
  const float* b_emb = (const float*)d_in[4];
  const float* Wg1   = (const float*)d_in[5];
  const float* bg1   = (const float*)d_in[6];
  const float* Wg2   = (const float*)d_in[7];
  const float* bg2   = (const float*)d_in[8];
  const float* eW1   = (const float*)d_in[9];
  const float* eb1   = (const float*)d_in[10];
  const float* eW2   = (const float*)d_in[11];
  const float* eb2   = (const float*)d_in[12];
  const float* nW1   = (const float*)d_in[13];
  const float* nb1   = (const float*)d_in[14];
  const float* nW2   = (const float*)d_in[15];
  const float* nb2   = (const float*)d_in[16];
  const float* deW1  = (const float*)d_in[17];
  const float* deb1  = (const float*)d_in[18];
  const float* deW2  = (const float*)d_in[19];
  const float* deb2  = (const float*)d_in[20];
  const float* dnW1  = (const float*)d_in[21];
  const float* dnb1  = (const float*)d_in[22];
  const float* dnW2  = (const float*)d_in[23];
  const float* dnb2  = (const float*)d_in[24];
  float* out = (float*)d_out;

  float* h   = (float*)d_ws;
  float* u   = h + N_NODES * 64;
  float* v   = u + N_NODES * 64;
  float* agg = v + N_NODES * 64;
  int* counts = (int*)(agg + N_NODES * 64);
  int* cursor = counts + N_NODES;
  int* bsum   = cursor + N_NODES;
  int* boffs  = bsum + 128;
  int* srow   = boffs + 128;
  int* scol   = srow + N_EDGES;
  float* sea  = (float*)(scol + N_EDGES);
  short* w2p  = (short*)(sea + N_EDGES);   // 6 x 8192 shorts (edge W2 tables)
  short* w1p  = w2p + 6 * 8192;            // 5 x 16384 shorts (nW1 tables)
  short* w2np = w1p + 5 * 16384;           // 5 x 8192 shorts (nW2 tables)
  short* uvp  = w2np + 5 * 8192;           // 5 x 16384 shorts (U|V tables)

  const int* rows = edges;
  const int* cols = edges + N_EDGES;

  // --- one-time preprocessing (graph static across layers) ---
  hipMemsetAsync(counts, 0, N_NODES * sizeof(int), stream);
  k_w2prep<<<6, 256, 0, stream>>>(eW2, deW2, w2p);
  k_nodeprep<<<400, 256, 0, stream>>>(nW1, nW2, eW1, deW1, w1p, w2np, uvp);
  k_hist<<<400, 256, 0, stream>>>(rows, counts);
  k_scanA<<<NB_SCAN, 256, 0, stream>>>(counts, bsum);
  k_scanB<<<1, 128, 0, stream>>>(bsum, boffs);
  k_scanC<<<NB_SCAN, 256, 0, stream>>>(counts, boffs, cursor);
  k_scatter<<<400, 256, 0, stream>>>(rows, cols, eatt, cursor, srow, scol, sea);

  // fused embed + layer-0 u/v (eb1 of layer 0 folded into u)
  k_embed_fused<<<NODE_TILES, 256, 0, stream>>>(nodes, W_emb, b_emb, Wg1, bg1,
                                                Wg2, bg2, eW1, eb1, h, u, v, agg);

  for (int i = 0; i < 5; ++i) {
    k_edge<<<EDGE_BLOCKS, 256, 0, stream>>>(u, v, srow, scol, sea,
                                            eW1 + i * 129 * 64 + 128 * 64,
                                            w2p + i * 8192, eb2 + i * 64, agg);
    const float* eb1next = (i < 4) ? (eb1 + (i + 1) * 64) : deb1;
    k_postfused<<<NODE_BLOCKS2, 256, 0, stream>>>(h, agg,
                                                  w1p + i * 16384, nb1 + i * 64,
                                                  w2np + i * 8192, nb2 + i * 64,
                                                  uvp + i * 16384, eb1next, u, v);
  }
  // decoder GCL edge pass
  k_edge<<<EDGE_BLOCKS, 256, 0, stream>>>(u, v, srow, scol, sea, deW1 + 128 * 64,
                                          w2p + 5 * 8192, deb2, agg);
  k_final_mfma<<<NODE_TILES, 256, 0, stream>>>(h, agg, dnW1, dnb1, dnW2, dnb2, out);
}